// Round 2
// baseline (359.903 us; speedup 1.0000x reference)
//
#include <hip/hip_runtime.h>
#include <hip/hip_bf16.h>

// QuantizedEmbedding: out[b,s,d] = (nib(packed[idx[b,s], d/2], d&1) - zeros[idx,g]) * scales[idx,g]
// D=1024, GROUP=64 -> 16 groups/row; packed has D/2=512 entries per row.
//
// HARNESS NOTE: all integer inputs arrive as int32 (one element per int32),
// so the uint8 packed table is delivered as int32[VOCAB*512] — row stride
// 2048 BYTES (262 MB table, ~L3-resident at 256 MiB).
//
// R5: 8 elems/thread (128 threads/row), lane-dense 8B loads + 16B nt stores.
// R6: 2 ROWS PER THREAD (block of 256 -> 4 rows). Rationale from counters:
//  - measured dur 358us = ~2x161us harness poison fills + ~36us kernel;
//    kernel floor at the fills' own 6.5 TB/s is ~24us -> latency headroom.
//  - each thread previously had a 2-deep dependent chain (idx load -> row
//    gather) with only 2 packed loads in flight. Now: row index load is
//    SGPR-uniform (s_load, off the VMEM critical path) and 4 independent
//    row-gathers + 8 param loads issue together -> 2x MLP, and per-row
//    addressing/instruction overhead halves.
//  - every load/store stays fully lane-dense (adjacent lanes -> adjacent
//    16B); stores stay nontemporal so the 262 MB table keeps L3 residency.
// R7: identical to R6 (previous bench died to a container-acquire infra
//     failure, no kernel signal). Only change: rely on compiler uniformity
//     for idxA/idxB instead of explicit readfirstlane.

#define D_DIM 1024
#define ROW_I32 512          // D/2 int32 entries per packed row
#define NGROUPS 16           // D/GROUP

typedef float vfloat4 __attribute__((ext_vector_type(4)));
typedef int   vint2   __attribute__((ext_vector_type(2)));

// (p.x, p.y) are two int32-held bytes -> 4 nibbles -> 4 floats.
// zs = -z*s precomputed so dequant is a single fma per element.
__device__ __forceinline__ vfloat4 dq(vint2 p, float s, float zs) {
    vfloat4 o;
    o.x = fmaf((float)(p.x & 0xF), s, zs);
    o.y = fmaf((float)(p.x >> 4 ), s, zs);
    o.z = fmaf((float)(p.y & 0xF), s, zs);
    o.w = fmaf((float)(p.y >> 4 ), s, zs);
    return o;
}

__global__ __launch_bounds__(256, 8) void qembed_kernel(
        const int* __restrict__ indices,
        const int* __restrict__ packed,    // int32 per original uint8 element
        const float* __restrict__ scales,
        const float* __restrict__ zeros,
        float* __restrict__ out,
        int n_rows) {
    int lane = threadIdx.x & 127;          // position within a row (128 thr/row)
    int pairsel = threadIdx.x >> 7;        // which row-pair of this block (0/1)

    // wave-uniform row id (waves 0-1: pairsel 0; waves 2-3: pairsel 1)
    int rowA = blockIdx.x * 4 + pairsel * 2;
    if (rowA >= n_rows) return;
    int hasB = (rowA + 1) < n_rows;        // n_rows=32768 -> always true; kept for safety
    int rowB = hasB ? rowA + 1 : rowA;

    // wave-uniform index loads -> scalar loads, off the VMEM critical path
    int idxA = indices[rowA];
    int idxB = indices[rowB];

    const int* prA = packed + (size_t)idxA * ROW_I32;
    const int* prB = packed + (size_t)idxB * ROW_I32;

    // 4 independent row-gathers, fully lane-dense (64 lanes x 8B = 512B each)
    vint2 a0 = *(const vint2*)(prA + 2 * lane);
    vint2 a1 = *(const vint2*)(prA + (ROW_I32 / 2) + 2 * lane);
    vint2 b0 = *(const vint2*)(prB + 2 * lane);
    vint2 b1 = *(const vint2*)(prB + (ROW_I32 / 2) + 2 * lane);

    int g0 = lane >> 4;                    // group of first segment (GROUP=64)
    int g1 = (NGROUPS / 2) + g0;           // group of second segment
    float sA0 = scales[idxA * NGROUPS + g0];
    float sA1 = scales[idxA * NGROUPS + g1];
    float sB0 = scales[idxB * NGROUPS + g0];
    float sB1 = scales[idxB * NGROUPS + g1];
    float zA0 = -zeros[idxA * NGROUPS + g0] * sA0;
    float zA1 = -zeros[idxA * NGROUPS + g1] * sA1;
    float zB0 = -zeros[idxB * NGROUPS + g0] * sB0;
    float zB1 = -zeros[idxB * NGROUPS + g1] * sB1;

    float* oA = out + (size_t)rowA * D_DIM;
    vfloat4 r;
    r = dq(a0, sA0, zA0);
    __builtin_nontemporal_store(r, (vfloat4*)(oA + 4 * lane));
    r = dq(a1, sA1, zA1);
    __builtin_nontemporal_store(r, (vfloat4*)(oA + (D_DIM / 2) + 4 * lane));

    if (hasB) {
        float* oB = out + (size_t)rowB * D_DIM;
        r = dq(b0, sB0, zB0);
        __builtin_nontemporal_store(r, (vfloat4*)(oB + 4 * lane));
        r = dq(b1, sB1, zB1);
        __builtin_nontemporal_store(r, (vfloat4*)(oB + (D_DIM / 2) + 4 * lane));
    }
}

extern "C" void kernel_launch(void* const* d_in, const int* in_sizes, int n_in,
                              void* d_out, int out_size, void* d_ws, size_t ws_size,
                              hipStream_t stream) {
    const int* indices = (const int*)d_in[0];
    const int* packed  = (const int*)d_in[1];
    const float* scales = (const float*)d_in[2];
    const float* zeros  = (const float*)d_in[3];
    float* out          = (float*)d_out;

    int n_rows = in_sizes[0];                 // B*S = 32768
    int block = 256;                          // 4 rows per block (2 per thread-pair)
    int grid = (n_rows + 3) / 4;

    qembed_kernel<<<grid, block, 0, stream>>>(indices, packed, scales, zeros, out, n_rows);
}